// Round 18
// baseline (364.122 us; speedup 1.0000x reference)
//
#include <hip/hip_runtime.h>
#include <hip/hip_bf16.h>
#include <stdint.h>

#define DIN    2048
#define MROWS  2048
#define LSEQ   512
#define NV     16384
#define DMODEL 1024
#define NC     8      // scan chunks
#define CL     64     // steps per chunk

typedef __attribute__((ext_vector_type(8))) short bf16x8;
typedef __attribute__((ext_vector_type(4))) float f32x4;
typedef __attribute__((ext_vector_type(16))) float f32x16;

__device__ __forceinline__ uint16_t f2bf(float f) {
  uint32_t u = __builtin_bit_cast(uint32_t, f);
  u += 0x7fffu + ((u >> 16) & 1u);
  return (uint16_t)(u >> 16);
}
__device__ __forceinline__ float bf2f(uint16_t u) {
  return __builtin_bit_cast(float, (uint32_t)u << 16);
}

__device__ __forceinline__ void gld_lds16(const uint16_t* g, uint16_t* l) {
  __builtin_amdgcn_global_load_lds(
      (const __attribute__((address_space(1))) void*)g,
      (__attribute__((address_space(3))) void*)l,
      16, 0, 0);
}

// ---------------------------------------------------------------------------
// r3 ring geometry, MFMA shape 32x32x16. 256x256 tile, BK=32, 8 waves,
// 4-slot LDS ring (128KB), counted vmcnt(8), XCD swizzle. Staging permutation
// UNCHANGED (phys_chunk = c ^ ((row>>1)&3)). B region starts at ELEMENT 8192
// within each slot (r17 bug: was 16384 = byte offset -> read next slot).
// Frag maps: A/B lane=row(l&31), k-octet=l>>5 contiguous 8;
// C/D col=l&31, row=(reg&3)+8*(reg>>2)+4*(l>>5).
// C = A(M,K)*B(N,K)^T fp32.
// ---------------------------------------------------------------------------
__global__ __launch_bounds__(512, 2) void gemm256_bf16_kernel(
    const uint16_t* __restrict__ A, const uint16_t* __restrict__ B,
    float* __restrict__ C, int M, int N, int K)
{
  __shared__ uint16_t lds[4 * 16384];   // 4 slots x (A 16KB | B 16KB)
  const int tid = threadIdx.x;
  const int w   = tid >> 6;
  const int l   = tid & 63;

  const int nwg = gridDim.x;
  const int cpx = nwg >> 3;
  const int swz = (blockIdx.x & 7) * cpx + (blockIdx.x >> 3);
  const int nmy = M >> 8;
  const int bm  = (swz % nmy) << 8;
  const int bn  = (swz / nmy) << 8;

  const int wr = w >> 2;     // 0..1
  const int wc = w & 3;      // 0..3

  // staging: source pre-swizzled, LDS dest linear (rule #21 pair) — unchanged
  const int srow = l >> 2;
  const int kof  = (((l & 3) ^ ((l >> 3) & 3)) << 3);
  const int ar0  = (w * 2 + 0) * 16 + srow;
  const int ar1  = (w * 2 + 1) * 16 + srow;
  const uint16_t* Ag0 = A + (size_t)(bm + ar0) * K + kof;
  const uint16_t* Ag1 = A + (size_t)(bm + ar1) * K + kof;
  const uint16_t* Bg0 = B + (size_t)(bn + ar0) * K + kof;
  const uint16_t* Bg1 = B + (size_t)(bn + ar1) * K + kof;
  const int lA0 = (w * 2 + 0) * 512;
  const int lA1 = (w * 2 + 1) * 512;
  const int lB0 = 8192 + (w * 2 + 0) * 512;
  const int lB1 = 8192 + (w * 2 + 1) * 512;

  // 32x32 frag read offsets: lane row lr = l&31, k-octet lk = l>>5,
  // swizzle term fx = (row>>1)&3 = (l>>1)&3 (per-lane const).
  const int lr = l & 31;
  const int lk = l >> 5;
  const int fx = (l >> 1) & 3;
  // elem offset of logical chunk c at row r: r*32 + ((c ^ fx) << 3)
  const int aBase = (wr * 128 + lr) * 32;           // + mi*1024 (32 rows * 32)
  const int bBase = 8192 + (wc * 64 + lr) * 32;     // + ni*1024  [FIXED: 8192 elems]
  const int cof0 = ((lk + 0) ^ fx) << 3;            // MFMA j=0: chunks 0/1
  const int cof1 = ((lk + 2) ^ fx) << 3;            // MFMA j=1: chunks 2/3

  f32x16 acc[4][2] = {};
  const int NT = K >> 5;

  auto stage = [&](int t) {
    const int sb = (t & 3) << 14;
    const int k0 = t << 5;
    gld_lds16(Ag0 + k0, lds + sb + lA0);
    gld_lds16(Ag1 + k0, lds + sb + lA1);
    gld_lds16(Bg0 + k0, lds + sb + lB0);
    gld_lds16(Bg1 + k0, lds + sb + lB1);
  };
  auto compute_tile = [&](int sb) {
    bf16x8 af[4][2], bfr[2][2];
#pragma unroll
    for (int mi = 0; mi < 4; ++mi) {
      af[mi][0] = *(const bf16x8*)(lds + sb + aBase + mi * 1024 + cof0);
      af[mi][1] = *(const bf16x8*)(lds + sb + aBase + mi * 1024 + cof1);
    }
#pragma unroll
    for (int ni = 0; ni < 2; ++ni) {
      bfr[ni][0] = *(const bf16x8*)(lds + sb + bBase + ni * 1024 + cof0);
      bfr[ni][1] = *(const bf16x8*)(lds + sb + bBase + ni * 1024 + cof1);
    }
    __builtin_amdgcn_s_setprio(1);
#pragma unroll
    for (int mi = 0; mi < 4; ++mi)
#pragma unroll
      for (int ni = 0; ni < 2; ++ni) {
        acc[mi][ni] = __builtin_amdgcn_mfma_f32_32x32x16_bf16(af[mi][0], bfr[ni][0], acc[mi][ni], 0, 0, 0);
        acc[mi][ni] = __builtin_amdgcn_mfma_f32_32x32x16_bf16(af[mi][1], bfr[ni][1], acc[mi][ni], 0, 0, 0);
      }
    __builtin_amdgcn_s_setprio(0);
  };

  // prologue: tiles 0..2 in flight (12 loads), wait tile 0 (leave 8)
  stage(0); stage(1); stage(2);
  asm volatile("s_waitcnt vmcnt(8)" ::: "memory");
  __builtin_amdgcn_s_barrier();

  for (int t = 0; t < NT - 3; ++t) {
    stage(t + 3);                       // slot (t+3)&3: consumed at iter t-1
    compute_tile((t & 3) << 14);
    asm volatile("s_waitcnt vmcnt(8)" ::: "memory");   // tile t+1 landed
    __builtin_amdgcn_s_barrier();
  }
  compute_tile(((NT - 3) & 3) << 14);
  asm volatile("s_waitcnt vmcnt(4)" ::: "memory");
  __builtin_amdgcn_s_barrier();
  compute_tile(((NT - 2) & 3) << 14);
  asm volatile("s_waitcnt vmcnt(0)" ::: "memory");
  __builtin_amdgcn_s_barrier();
  compute_tile(((NT - 1) & 3) << 14);

  // epilogue: C/D 32x32 map — col = l&31, row = (reg&3)+8*(reg>>2)+4*(l>>5)
#pragma unroll
  for (int mi = 0; mi < 4; ++mi) {
#pragma unroll
    for (int ni = 0; ni < 2; ++ni) {
      const int c0 = bn + wc * 64 + ni * 32 + lr;
#pragma unroll
      for (int reg = 0; reg < 16; ++reg) {
        const int r0 = bm + wr * 128 + mi * 32 + (reg & 3) + 8 * (reg >> 2) + 4 * lk;
        C[(size_t)r0 * N + c0] = acc[mi][ni][reg];
      }
    }
  }
}

// ---------------------------------------------------------------------------
// 128x128 kernel: chunk-XOR LDS swizzle; fp32 OR bf16 output; optional fused
// bias+softplus epilogue. Split-K via gridDim.z (fp32 path only).
// ---------------------------------------------------------------------------
__global__ __launch_bounds__(256) void gemm_bf16_kernel(
    const uint16_t* __restrict__ A, const uint16_t* __restrict__ B,
    float* __restrict__ Cf, uint16_t* __restrict__ Cbf,
    int M, int N, int K, int kchunk, const float* __restrict__ bias)
{
  __shared__ uint16_t As[128 * 32];
  __shared__ uint16_t Bs[128 * 32];
  const int tid  = threadIdx.x;
  const int wid  = tid >> 6;
  const int lane = tid & 63;
  const int bm = blockIdx.y * 128;
  const int bn = blockIdx.x * 128;
  const int k_beg = blockIdx.z * kchunk;
  float* Cout = Cf + (size_t)blockIdx.z * M * N;

  const int fr = lane & 15;
  const int fg = lane >> 4;
  const int wm = (wid >> 1) * 64;
  const int wn = (wid & 1) * 64;

  const int srow = wid * 32 + (lane >> 2);
  const int skof = (((lane & 3) ^ ((lane >> 2) & 3)) << 3);
  const uint16_t* Ag = A + (size_t)(bm + srow) * K + skof;
  const uint16_t* Bg = B + (size_t)(bn + srow) * K + skof;
  uint16_t* Al = As + wid * 1024;
  uint16_t* Bl = Bs + wid * 1024;

  const int cxr = ((fg ^ (fr & 3)) << 3);

  f32x4 acc[4][4] = {};

  for (int k0 = 0; k0 < kchunk; k0 += 32) {
    const int kk = k_beg + k0;
    gld_lds16(Ag + kk, Al);
    gld_lds16(Ag + (size_t)16 * K + kk, Al + 512);
    gld_lds16(Bg + kk, Bl);
    gld_lds16(Bg + (size_t)16 * K + kk, Bl + 512);
    asm volatile("s_waitcnt vmcnt(0)" ::: "memory");
    __syncthreads();
    bf16x8 af[4], bfr[4];
#pragma unroll
    for (int i = 0; i < 4; ++i)
      af[i] = *(const bf16x8*)(As + (wm + i * 16 + fr) * 32 + cxr);
#pragma unroll
    for (int j = 0; j < 4; ++j)
      bfr[j] = *(const bf16x8*)(Bs + (wn + j * 16 + fr) * 32 + cxr);
#pragma unroll
    for (int i = 0; i < 4; ++i)
#pragma unroll
      for (int j = 0; j < 4; ++j)
        acc[i][j] = __builtin_amdgcn_mfma_f32_16x16x32_bf16(af[i], bfr[j], acc[i][j], 0, 0, 0);
    __syncthreads();
  }

#pragma unroll
  for (int i = 0; i < 4; ++i) {
    const int r0 = bm + wm + i * 16 + fg * 4;
#pragma unroll
    for (int j = 0; j < 4; ++j) {
      const int c0 = bn + wn + j * 16 + fr;
      const float bv = bias ? bias[c0] : 0.f;
#pragma unroll
      for (int r = 0; r < 4; ++r) {
        float v = acc[i][j][r];
        if (bias) {
          const float u = v + bv;
          v = (u > 20.f) ? u : log1pf(__expf(u));
        }
        if (Cbf) Cbf[(size_t)(r0 + r) * N + c0] = f2bf(v);
        else     Cout[(size_t)(r0 + r) * N + c0] = v;
      }
    }
  }
}

// ---------------------------------------------------------------------------
// mega conversion kernel: embed gather | in_proj_w | out_proj_w | dt_proj_w |
// x_proj_w pad | recon_w -> bf16, one launch.
// ---------------------------------------------------------------------------
__global__ __launch_bounds__(256) void mega_cvt_kernel(
    const int* __restrict__ tok, const float* __restrict__ emb,
    const float* __restrict__ wi, const float* __restrict__ wo,
    const float* __restrict__ wdt, const float* __restrict__ wx,
    const float* __restrict__ wr,
    uint16_t* __restrict__ hb, uint16_t* __restrict__ wib,
    uint16_t* __restrict__ wob, uint16_t* __restrict__ wdtb,
    uint16_t* __restrict__ wxb, uint16_t* __restrict__ wrb)
{
  const int bid = blockIdx.x;
  if (bid < 2048) {
    const int m = bid;
    const int t = tok[m];
    const float4 v = ((const float4*)(emb + (size_t)t * DMODEL))[threadIdx.x];
    ((ushort4*)(hb + (size_t)m * DMODEL))[threadIdx.x] =
        make_ushort4(f2bf(v.x), f2bf(v.y), f2bf(v.z), f2bf(v.w));
  } else if (bid < 6144) {
    const int i = (bid - 2048) * 256 + threadIdx.x;
    const float4 v = ((const float4*)wi)[i];
    ((ushort4*)wib)[i] = make_ushort4(f2bf(v.x), f2bf(v.y), f2bf(v.z), f2bf(v.w));
  } else if (bid < 8192) {
    const int i = (bid - 6144) * 256 + threadIdx.x;
    const float4 v = ((const float4*)wo)[i];
    ((ushort4*)wob)[i] = make_ushort4(f2bf(v.x), f2bf(v.y), f2bf(v.z), f2bf(v.w));
  } else if (bid < 8320) {
    const int i = (bid - 8192) * 256 + threadIdx.x;
    const float4 v = ((const float4*)wdt)[i];
    ((ushort4*)wdtb)[i] = make_ushort4(f2bf(v.x), f2bf(v.y), f2bf(v.z), f2bf(v.w));
  } else if (bid < 8576) {
    const int i = (bid - 8320) * 256 + threadIdx.x;
    const int r = i >> 9, c = i & 511;
    ushort4 o = make_ushort4(0, 0, 0, 0);
    if (r < 96) {
      const float4 v = ((const float4*)wx)[(size_t)r * 512 + c];
      o = make_ushort4(f2bf(v.x), f2bf(v.y), f2bf(v.z), f2bf(v.w));
    }
    ((ushort4*)wxb)[i] = o;
  } else {
    const int i = (bid - 8576) * 256 + threadIdx.x;   // 4194304 f4 (recon_w)
    const float4 v = ((const float4*)wr)[i];
    ((ushort4*)wrb)[i] = make_ushort4(f2bf(v.x), f2bf(v.y), f2bf(v.z), f2bf(v.w));
  }
}

// x_proj split-K reduce (8 slices) + dt slice -> bf16
__global__ __launch_bounds__(256) void reduce8_dt_kernel(
    const float* __restrict__ in, float* __restrict__ xdbl, uint16_t* __restrict__ dtb) {
  const int i = blockIdx.x * 256 + threadIdx.x;   // 262144 = 2048*128
  float s = 0.f;
#pragma unroll
  for (int z = 0; z < 8; ++z) s += in[i + (size_t)z * 262144];
  xdbl[i] = s;
  const int c = i & 127;
  if (c < 64) dtb[(i >> 7) * 64 + c] = f2bf(s);
}

// out_proj split-K reduce (2 slices) -> bf16 h2
__global__ __launch_bounds__(256) void reduce2_bf16_kernel(
    const float* __restrict__ in, uint16_t* __restrict__ outb, int n) {
  const int i = blockIdx.x * 256 + threadIdx.x;
  if (i >= n) return;
  outb[i] = f2bf(in[i] + in[i + (size_t)n]);
}

// causal conv (K=4) + bias + silu; bf16 in/out. 4 d per thread.
__global__ __launch_bounds__(256) void conv_silu_kernel(
    const uint16_t* __restrict__ xzb, const float* __restrict__ cw, const float* __restrict__ cb,
    uint16_t* __restrict__ xcb)
{
  const int idx = blockIdx.x * 256 + threadIdx.x;  // (m, d/4): 2048*512 total
  const int d4  = idx & 511;
  const int m   = idx >> 9;
  const int l   = m & (LSEQ - 1);
  const int d   = d4 << 2;
  const float4 cbv = *(const float4*)(cb + d);
  float a0 = cbv.x, a1 = cbv.y, a2 = cbv.z, a3 = cbv.w;
  const float4 w0 = *(const float4*)(cw + (d + 0) * 4);
  const float4 w1 = *(const float4*)(cw + (d + 1) * 4);
  const float4 w2 = *(const float4*)(cw + (d + 2) * 4);
  const float4 w3 = *(const float4*)(cw + (d + 3) * 4);
  const float wj0[4] = {w0.x, w0.y, w0.z, w0.w};
  const float wj1[4] = {w1.x, w1.y, w1.z, w1.w};
  const float wj2[4] = {w2.x, w2.y, w2.z, w2.w};
  const float wj3[4] = {w3.x, w3.y, w3.z, w3.w};
#pragma unroll
  for (int j = 0; j < 4; ++j) {
    const int lj = l - 3 + j;
    if (lj >= 0) {
      const ushort4 x = *(const ushort4*)(xzb + (size_t)(m - 3 + j) * 4096 + d);
      a0 += wj0[j] * bf2f(x.x);
      a1 += wj1[j] * bf2f(x.y);
      a2 += wj2[j] * bf2f(x.z);
      a3 += wj3[j] * bf2f(x.w);
    }
  }
  const float r0 = a0 / (1.f + __expf(-a0));
  const float r1 = a1 / (1.f + __expf(-a1));
  const float r2 = a2 / (1.f + __expf(-a2));
  const float r3 = a3 / (1.f + __expf(-a3));
  *(ushort4*)(xcb + (size_t)m * DIN + d) = make_ushort4(f2bf(r0), f2bf(r1), f2bf(r2), f2bf(r3));
}

// ---------------------------------------------------------------------------
// chunked scan, r8 q-split layout (measured best): thread per (d,q), 4 states.
// scan_final composes its own boundary state from P/Q (<=7 fused steps).
// ---------------------------------------------------------------------------
__global__ __launch_bounds__(256) void scan_partial_kernel(
    const uint16_t* __restrict__ delta_bf, const uint16_t* __restrict__ xcb,
    const float* __restrict__ xdbl, const float* __restrict__ A_log,
    float* __restrict__ Pb, float* __restrict__ Qb)
{
  const int q = threadIdx.x & 3;
  const int d_idx = threadIdx.x >> 2;
  const int c = blockIdx.x;
  const int d = blockIdx.y * 64 + d_idx;
  const int b = blockIdx.z;
  float Arow[4];
#pragma unroll
  for (int n = 0; n < 4; ++n)
    Arow[n] = -expf(A_log[d * 16 + q * 4 + n]);
  float P[4] = {1.f, 1.f, 1.f, 1.f};
  float Q[4] = {0.f, 0.f, 0.f, 0.f};
  const int l0 = c * CL;
#pragma unroll 4
  for (int li = 0; li < CL; ++li) {
    const int m = b * LSEQ + l0 + li;
    const float de = bf2f(delta_bf[(size_t)m * DIN + d]);
    const float xv = bf2f(xcb[(size_t)m * DIN + d]);
    const float dx = de * xv;
    const float4 Bv = *(const float4*)(xdbl + (size_t)m * 128 + 64 + q * 4);
    const float bv[4] = {Bv.x, Bv.y, Bv.z, Bv.w};
#pragma unroll
    for (int n = 0; n < 4; ++n) {
      const float a = __expf(de * Arow[n]);
      P[n] *= a;
      Q[n] = a * Q[n] + dx * bv[n];
    }
  }
  const size_t o = ((size_t)(b * NC + c) * DIN + d) * 16 + q * 4;
  *(float4*)(Pb + o) = make_float4(P[0], P[1], P[2], P[3]);
  *(float4*)(Qb + o) = make_float4(Q[0], Q[1], Q[2], Q[3]);
}

__global__ __launch_bounds__(256) void scan_final_kernel(
    const uint16_t* __restrict__ delta_bf, const uint16_t* __restrict__ xcb,
    const float* __restrict__ xdbl, const uint16_t* __restrict__ xzb,
    const float* __restrict__ A_log, const float* __restrict__ Dp,
    const float* __restrict__ Pb, const float* __restrict__ Qb,
    uint16_t* __restrict__ yb)
{
  const int q = threadIdx.x & 3;
  const int d_idx = threadIdx.x >> 2;
  const int c = blockIdx.x;
  const int d = blockIdx.y * 64 + d_idx;
  const int b = blockIdx.z;
  float Arow[4];
#pragma unroll
  for (int n = 0; n < 4; ++n)
    Arow[n] = -expf(A_log[d * 16 + q * 4 + n]);
  const float dpd = Dp[d];
  float h[4] = {0.f, 0.f, 0.f, 0.f};
  for (int cc = 0; cc < c; ++cc) {
    const size_t o = ((size_t)(b * NC + cc) * DIN + d) * 16 + q * 4;
    const float4 P4 = *(const float4*)(Pb + o);
    const float4 Q4 = *(const float4*)(Qb + o);
    h[0] = P4.x * h[0] + Q4.x;
    h[1] = P4.y * h[1] + Q4.y;
    h[2] = P4.z * h[2] + Q4.z;
    h[3] = P4.w * h[3] + Q4.w;
  }
  const int l0 = c * CL;
#pragma unroll 2
  for (int li = 0; li < CL; ++li) {
    const int m = b * LSEQ + l0 + li;
    const float de = bf2f(delta_bf[(size_t)m * DIN + d]);
    const float xv = bf2f(xcb[(size_t)m * DIN + d]);
    const float dx = de * xv;
    const float4 Bv = *(const float4*)(xdbl + (size_t)m * 128 + 64 + q * 4);
    const float4 Cv = *(const float4*)(xdbl + (size_t)m * 128 + 80 + q * 4);
    const float bv[4] = {Bv.x, Bv.y, Bv.z, Bv.w};
    const float cv[4] = {Cv.x, Cv.y, Cv.z, Cv.w};
    float yp = 0.f;
#pragma unroll
    for (int n = 0; n < 4; ++n) {
      const float a = __expf(de * Arow[n]);
      h[n] = a * h[n] + dx * bv[n];
      yp += h[n] * cv[n];
    }
    yp += __shfl_xor(yp, 1);
    yp += __shfl_xor(yp, 2);
    if (q == 0) {
      const float z = bf2f(xzb[(size_t)m * 4096 + 2048 + d]);
      const float sil = z / (1.f + __expf(-z));
      yb[(size_t)m * DIN + d] = f2bf((yp + xv * dpd) * sil);
    }
  }
}

// mean-pool partials: block (b,s) sums 32 L-rows of bf16 h2
__global__ __launch_bounds__(256) void pool1_kernel(
    const uint16_t* __restrict__ h2b, float* __restrict__ part) {
  const int b = blockIdx.x >> 4, s = blockIdx.x & 15;
  const int c = threadIdx.x * 4;
  const uint16_t* base = h2b + ((size_t)(b * LSEQ + s * 32)) * DMODEL + c;
  float a0 = 0, a1 = 0, a2 = 0, a3 = 0;
  for (int l = 0; l < 32; ++l) {
    const ushort4 v = *(const ushort4*)(base + (size_t)l * DMODEL);
    a0 += bf2f(v.x); a1 += bf2f(v.y); a2 += bf2f(v.z); a3 += bf2f(v.w);
  }
  *(float4*)(part + (size_t)blockIdx.x * DMODEL + c) = make_float4(a0, a1, a2, a3);
}

// final pool reduce + CLS head, one block per batch
__global__ __launch_bounds__(256) void pool2_cls_kernel(
    const float* __restrict__ part, const float* __restrict__ w, float* __restrict__ out) {
  __shared__ float pl[DMODEL];
  const int b = blockIdx.x, t = threadIdx.x;
  float4 s = make_float4(0, 0, 0, 0);
  for (int k = 0; k < 16; ++k) {
    const float4 v = *(const float4*)(part + ((size_t)(b * 16 + k)) * DMODEL + t * 4);
    s.x += v.x; s.y += v.y; s.z += v.z; s.w += v.w;
  }
  const float inv = 1.f / (float)LSEQ;
  pl[t * 4 + 0] = s.x * inv; pl[t * 4 + 1] = s.y * inv;
  pl[t * 4 + 2] = s.z * inv; pl[t * 4 + 3] = s.w * inv;
  __syncthreads();
  if (t < 128) {
    const float* wr = w + (size_t)t * DMODEL;
    float acc = 0.f;
    for (int k = 0; k < DMODEL; ++k) acc += pl[k] * wr[k];
    out[b * 128 + t] = acc;
  }
}

extern "C" void kernel_launch(void* const* d_in, const int* in_sizes, int n_in,
                              void* d_out, int out_size, void* d_ws, size_t ws_size,
                              hipStream_t stream) {
  const int*   tokens    = (const int*)d_in[0];
  const float* embedding = (const float*)d_in[1];
  const float* in_proj_w = (const float*)d_in[2];
  const float* conv_w    = (const float*)d_in[3];
  const float* conv_b    = (const float*)d_in[4];
  const float* x_proj_w  = (const float*)d_in[5];
  const float* dt_proj_w = (const float*)d_in[6];
  const float* dt_proj_b = (const float*)d_in[7];
  const float* A_log     = (const float*)d_in[8];
  const float* D_param   = (const float*)d_in[9];
  const float* out_prj_w = (const float*)d_in[10];
  const float* recon_w   = (const float*)d_in[11];
  const float* cls_w     = (const float*)d_in[12];

  char* ws = (char*)d_ws;
  const size_t MB = 1024 * 1024;
  uint16_t* h_bf   = (uint16_t*)(ws + 0);                 // 0-4   [dead after in_proj]
  uint16_t* w_in   = (uint16_t*)(ws + 4 * MB);            // 4-12  [dead after in_proj]
  uint16_t* xz_bf  = (uint16_t*)(ws + 12 * MB);           // 12-28 [dead after scan_final]
  uint16_t* xc_b   = (uint16_t*)(ws + 28 * MB);           // 28-36
  uint16_t* wx_bf  = (uint16_t*)(ws + 36 * MB);           // 36-36.5
  uint16_t* dt_bf  = (uint16_t*)(ws + 36 * MB + 512 * 1024);   // 36.5-36.75
  uint16_t* wdt_bf = (uint16_t*)(ws + 36 * MB + 768 * 1024);   // 36.75-37
  float*    xdbl   = (float*)(ws + 37 * MB);              // 37-38
  uint16_t* delt_b = (uint16_t*)(ws + 38 * MB);           // 38-46 (bf16 delta)
  float*    kscr   = (float*)(ws + 46 * MB);              // 46-54 (x_proj splitK x8; dead after reduce8)
  uint16_t* y_bf   = (uint16_t*)(ws + 54 * MB);           // 54-62
  uint16_t* h2_bf  = (uint16_t*)(ws + 62 * MB);           // 62-66
  uint16_t* wout_bf= (uint16_t*)(ws + 66 * MB);           // 66-70
  float*    part   = (float*)(ws + 70 * MB);              // 70-70.25
  uint16_t* wrec_bf= (uint16_t*)(ws + 71 * MB);           // 71-103 (written step 1, read by recon)
  // aliases (lifetime-disjoint)
  float*    Pbuf   = (float*)(ws + 46 * MB);              // 46-50 (kscr dead)
  float*    Qbuf   = (float*)(ws + 50 * MB);              // 50-54
  float*    kscr2  = (float*)(ws + 4 * MB);               // 4-20 (w_in + xz_bf dead by out_proj)

  const int RECON = MROWS * NV;

  // 1. ALL conversions (incl. recon_w) + embedding gather, one launch
  mega_cvt_kernel<<<dim3(24960), dim3(256), 0, stream>>>(
      tokens, embedding, in_proj_w, out_prj_w, dt_proj_w, x_proj_w, recon_w,
      h_bf, w_in, wout_bf, wdt_bf, wx_bf, wrec_bf);
  // 2. in_proj: 2048 x 4096, K=1024 -> bf16 xz directly
  gemm_bf16_kernel<<<dim3(32, 16, 1), dim3(256), 0, stream>>>(h_bf, w_in, nullptr, xz_bf, MROWS, 4096, 1024, 1024, nullptr);
  // 3. causal conv + silu (bf16 in/out)
  conv_silu_kernel<<<dim3(4096), dim3(256), 0, stream>>>(xz_bf, conv_w, conv_b, xc_b);
  // 4. x_dbl = x @ x_proj_w^T (split-K x8 -> 128 blocks)
  gemm_bf16_kernel<<<dim3(1, 16, 8), dim3(256), 0, stream>>>(xc_b, wx_bf, kscr, nullptr, MROWS, 128, 2048, 256, nullptr);
  reduce8_dt_kernel<<<dim3(1024), dim3(256), 0, stream>>>(kscr, xdbl, dt_bf);
  // 5. delta = softplus(dt @ dt_proj_w^T + b) -> bf16
  gemm_bf16_kernel<<<dim3(16, 16, 1), dim3(256), 0, stream>>>(dt_bf, wdt_bf, nullptr, delt_b, MROWS, DIN, 64, 64, dt_proj_b);
  // 6. chunked selective scan (bounds folded into scan_final prologue)
  scan_partial_kernel<<<dim3(NC, 32, 4), dim3(256), 0, stream>>>(delt_b, xc_b, xdbl, A_log, Pbuf, Qbuf);
  scan_final_kernel<<<dim3(NC, 32, 4), dim3(256), 0, stream>>>(delt_b, xc_b, xdbl, xz_bf, A_log, D_param, Pbuf, Qbuf, y_bf);
  // 7. out_proj: split-K x2 (256 blocks) + bf16 reduce
  gemm_bf16_kernel<<<dim3(8, 16, 2), dim3(256), 0, stream>>>(y_bf, wout_bf, kscr2, nullptr, MROWS, 1024, 2048, 1024, nullptr);
  reduce2_bf16_kernel<<<dim3(8192), dim3(256), 0, stream>>>(kscr2, h2_bf, MROWS * 1024);
  // 8. recon: 2048 x 16384, K=1024 (r3 ring, 32x32x16 MFMA)
  gemm256_bf16_kernel<<<dim3(512), dim3(512), 0, stream>>>(h2_bf, wrec_bf, (float*)d_out, MROWS, NV, 1024);
  // 9. CLS head
  pool1_kernel<<<dim3(64), dim3(256), 0, stream>>>(h2_bf, part);
  pool2_cls_kernel<<<dim3(4), dim3(256), 0, stream>>>(part, cls_w, (float*)d_out + RECON);
}

// Round 19
// 357.831 us; speedup vs baseline: 1.0176x; 1.0176x over previous
//
#include <hip/hip_runtime.h>
#include <hip/hip_bf16.h>
#include <stdint.h>

#define DIN    2048
#define MROWS  2048
#define LSEQ   512
#define NV     16384
#define DMODEL 1024
#define NC     8      // scan chunks
#define CL     64     // steps per chunk

typedef __attribute__((ext_vector_type(8))) short bf16x8;
typedef __attribute__((ext_vector_type(4))) float f32x4;

__device__ __forceinline__ uint16_t f2bf(float f) {
  uint32_t u = __builtin_bit_cast(uint32_t, f);
  u += 0x7fffu + ((u >> 16) & 1u);
  return (uint16_t)(u >> 16);
}
__device__ __forceinline__ float bf2f(uint16_t u) {
  return __builtin_bit_cast(float, (uint32_t)u << 16);
}

__device__ __forceinline__ void gld_lds16(const uint16_t* g, uint16_t* l) {
  __builtin_amdgcn_global_load_lds(
      (const __attribute__((address_space(1))) void*)g,
      (__attribute__((address_space(3))) void*)l,
      16, 0, 0);
}

// ---------------------------------------------------------------------------
// r3 ring (measured best recon: ~83us / 830 TF): 256x256 tile, BK=32, 8 waves,
// 4-slot LDS ring (128KB), counted vmcnt(8), XOR swizzle (0 conflicts for the
// 16x16 read pattern), XCD swizzle. C = A(M,K)*B(N,K)^T fp32.
// NOTE (r18): 32x32x16 MFMA variant regressed (+8us, 6.3M bank conflicts) —
// the period-8 chunk-XOR cannot spread 32-row fragment reads. Keep 16x16.
// ---------------------------------------------------------------------------
__global__ __launch_bounds__(512, 2) void gemm256_bf16_kernel(
    const uint16_t* __restrict__ A, const uint16_t* __restrict__ B,
    float* __restrict__ C, int M, int N, int K)
{
  __shared__ uint16_t lds[4 * 16384];   // 4 slots x (A 16KB | B 16KB)
  const int tid = threadIdx.x;
  const int w   = tid >> 6;
  const int l   = tid & 63;

  const int nwg = gridDim.x;
  const int cpx = nwg >> 3;
  const int swz = (blockIdx.x & 7) * cpx + (blockIdx.x >> 3);
  const int nmy = M >> 8;
  const int bm  = (swz % nmy) << 8;
  const int bn  = (swz / nmy) << 8;

  const int fr = l & 15;
  const int fg = l >> 4;
  const int wr = w >> 2;     // 0..1
  const int wc = w & 3;      // 0..3

  // staging: source pre-swizzled, LDS dest linear (rule #21 pair)
  const int srow = l >> 2;
  const int kof  = (((l & 3) ^ ((l >> 3) & 3)) << 3);
  const int ar0  = (w * 2 + 0) * 16 + srow;
  const int ar1  = (w * 2 + 1) * 16 + srow;
  const uint16_t* Ag0 = A + (size_t)(bm + ar0) * K + kof;
  const uint16_t* Ag1 = A + (size_t)(bm + ar1) * K + kof;
  const uint16_t* Bg0 = B + (size_t)(bn + ar0) * K + kof;
  const uint16_t* Bg1 = B + (size_t)(bn + ar1) * K + kof;
  const int lA0 = (w * 2 + 0) * 512;
  const int lA1 = (w * 2 + 1) * 512;
  const int lB0 = 8192 + (w * 2 + 0) * 512;
  const int lB1 = 8192 + (w * 2 + 1) * 512;

  // swizzled ds_read offsets
  const int axr  = ((fg ^ ((fr >> 1) & 3)) << 3);
  const int aoff = (wr * 128 + fr) * 32 + axr;          // + mi*512
  const int boff = 8192 + (wc * 64 + fr) * 32 + axr;    // + ni*512

  f32x4 acc[8][4] = {};
  const int NT = K >> 5;

  auto stage = [&](int t) {
    const int sb = (t & 3) << 14;
    const int k0 = t << 5;
    gld_lds16(Ag0 + k0, lds + sb + lA0);
    gld_lds16(Ag1 + k0, lds + sb + lA1);
    gld_lds16(Bg0 + k0, lds + sb + lB0);
    gld_lds16(Bg1 + k0, lds + sb + lB1);
  };
  auto compute_tile = [&](int sb) {
    bf16x8 af[8], bfr[4];
#pragma unroll
    for (int mi = 0; mi < 8; ++mi)
      af[mi] = *(const bf16x8*)(lds + sb + aoff + mi * 512);
#pragma unroll
    for (int ni = 0; ni < 4; ++ni)
      bfr[ni] = *(const bf16x8*)(lds + sb + boff + ni * 512);
    __builtin_amdgcn_s_setprio(1);
#pragma unroll
    for (int mi = 0; mi < 8; ++mi)
#pragma unroll
      for (int ni = 0; ni < 4; ++ni)
        acc[mi][ni] = __builtin_amdgcn_mfma_f32_16x16x32_bf16(af[mi], bfr[ni], acc[mi][ni], 0, 0, 0);
    __builtin_amdgcn_s_setprio(0);
  };

  // prologue: tiles 0..2 in flight (12 loads), wait tile 0 (leave 8)
  stage(0); stage(1); stage(2);
  asm volatile("s_waitcnt vmcnt(8)" ::: "memory");
  __builtin_amdgcn_s_barrier();

  for (int t = 0; t < NT - 3; ++t) {
    stage(t + 3);                       // slot (t+3)&3: consumed at iter t-1
    compute_tile((t & 3) << 14);
    asm volatile("s_waitcnt vmcnt(8)" ::: "memory");   // tile t+1 landed
    __builtin_amdgcn_s_barrier();
  }
  compute_tile(((NT - 3) & 3) << 14);
  asm volatile("s_waitcnt vmcnt(4)" ::: "memory");
  __builtin_amdgcn_s_barrier();
  compute_tile(((NT - 2) & 3) << 14);
  asm volatile("s_waitcnt vmcnt(0)" ::: "memory");
  __builtin_amdgcn_s_barrier();
  compute_tile(((NT - 1) & 3) << 14);

#pragma unroll
  for (int mi = 0; mi < 8; ++mi) {
    const int r0 = bm + wr * 128 + mi * 16 + fg * 4;
#pragma unroll
    for (int ni = 0; ni < 4; ++ni) {
      const int c0 = bn + wc * 64 + ni * 16 + fr;
#pragma unroll
      for (int r = 0; r < 4; ++r)
        C[(size_t)(r0 + r) * N + c0] = acc[mi][ni][r];
    }
  }
}

// ---------------------------------------------------------------------------
// 128x128 kernel: chunk-XOR LDS swizzle; fp32 OR bf16 output; optional fused
// bias+softplus epilogue. Split-K via gridDim.z (fp32 path only).
// ---------------------------------------------------------------------------
__global__ __launch_bounds__(256) void gemm_bf16_kernel(
    const uint16_t* __restrict__ A, const uint16_t* __restrict__ B,
    float* __restrict__ Cf, uint16_t* __restrict__ Cbf,
    int M, int N, int K, int kchunk, const float* __restrict__ bias)
{
  __shared__ uint16_t As[128 * 32];
  __shared__ uint16_t Bs[128 * 32];
  const int tid  = threadIdx.x;
  const int wid  = tid >> 6;
  const int lane = tid & 63;
  const int bm = blockIdx.y * 128;
  const int bn = blockIdx.x * 128;
  const int k_beg = blockIdx.z * kchunk;
  float* Cout = Cf + (size_t)blockIdx.z * M * N;

  const int fr = lane & 15;
  const int fg = lane >> 4;
  const int wm = (wid >> 1) * 64;
  const int wn = (wid & 1) * 64;

  const int srow = wid * 32 + (lane >> 2);
  const int skof = (((lane & 3) ^ ((lane >> 2) & 3)) << 3);
  const uint16_t* Ag = A + (size_t)(bm + srow) * K + skof;
  const uint16_t* Bg = B + (size_t)(bn + srow) * K + skof;
  uint16_t* Al = As + wid * 1024;
  uint16_t* Bl = Bs + wid * 1024;

  const int cxr = ((fg ^ (fr & 3)) << 3);

  f32x4 acc[4][4] = {};

  for (int k0 = 0; k0 < kchunk; k0 += 32) {
    const int kk = k_beg + k0;
    gld_lds16(Ag + kk, Al);
    gld_lds16(Ag + (size_t)16 * K + kk, Al + 512);
    gld_lds16(Bg + kk, Bl);
    gld_lds16(Bg + (size_t)16 * K + kk, Bl + 512);
    asm volatile("s_waitcnt vmcnt(0)" ::: "memory");
    __syncthreads();
    bf16x8 af[4], bfr[4];
#pragma unroll
    for (int i = 0; i < 4; ++i)
      af[i] = *(const bf16x8*)(As + (wm + i * 16 + fr) * 32 + cxr);
#pragma unroll
    for (int j = 0; j < 4; ++j)
      bfr[j] = *(const bf16x8*)(Bs + (wn + j * 16 + fr) * 32 + cxr);
#pragma unroll
    for (int i = 0; i < 4; ++i)
#pragma unroll
      for (int j = 0; j < 4; ++j)
        acc[i][j] = __builtin_amdgcn_mfma_f32_16x16x32_bf16(af[i], bfr[j], acc[i][j], 0, 0, 0);
    __syncthreads();
  }

#pragma unroll
  for (int i = 0; i < 4; ++i) {
    const int r0 = bm + wm + i * 16 + fg * 4;
#pragma unroll
    for (int j = 0; j < 4; ++j) {
      const int c0 = bn + wn + j * 16 + fr;
      const float bv = bias ? bias[c0] : 0.f;
#pragma unroll
      for (int r = 0; r < 4; ++r) {
        float v = acc[i][j][r];
        if (bias) {
          const float u = v + bv;
          v = (u > 20.f) ? u : log1pf(__expf(u));
        }
        if (Cbf) Cbf[(size_t)(r0 + r) * N + c0] = f2bf(v);
        else     Cout[(size_t)(r0 + r) * N + c0] = v;
      }
    }
  }
}

// ---------------------------------------------------------------------------
// mega conversion kernel: embed gather | in_proj_w | out_proj_w | dt_proj_w |
// x_proj_w pad | recon_w -> bf16, one launch.
// ---------------------------------------------------------------------------
__global__ __launch_bounds__(256) void mega_cvt_kernel(
    const int* __restrict__ tok, const float* __restrict__ emb,
    const float* __restrict__ wi, const float* __restrict__ wo,
    const float* __restrict__ wdt, const float* __restrict__ wx,
    const float* __restrict__ wr,
    uint16_t* __restrict__ hb, uint16_t* __restrict__ wib,
    uint16_t* __restrict__ wob, uint16_t* __restrict__ wdtb,
    uint16_t* __restrict__ wxb, uint16_t* __restrict__ wrb)
{
  const int bid = blockIdx.x;
  if (bid < 2048) {
    const int m = bid;
    const int t = tok[m];
    const float4 v = ((const float4*)(emb + (size_t)t * DMODEL))[threadIdx.x];
    ((ushort4*)(hb + (size_t)m * DMODEL))[threadIdx.x] =
        make_ushort4(f2bf(v.x), f2bf(v.y), f2bf(v.z), f2bf(v.w));
  } else if (bid < 6144) {
    const int i = (bid - 2048) * 256 + threadIdx.x;
    const float4 v = ((const float4*)wi)[i];
    ((ushort4*)wib)[i] = make_ushort4(f2bf(v.x), f2bf(v.y), f2bf(v.z), f2bf(v.w));
  } else if (bid < 8192) {
    const int i = (bid - 6144) * 256 + threadIdx.x;
    const float4 v = ((const float4*)wo)[i];
    ((ushort4*)wob)[i] = make_ushort4(f2bf(v.x), f2bf(v.y), f2bf(v.z), f2bf(v.w));
  } else if (bid < 8320) {
    const int i = (bid - 8192) * 256 + threadIdx.x;
    const float4 v = ((const float4*)wdt)[i];
    ((ushort4*)wdtb)[i] = make_ushort4(f2bf(v.x), f2bf(v.y), f2bf(v.z), f2bf(v.w));
  } else if (bid < 8576) {
    const int i = (bid - 8320) * 256 + threadIdx.x;
    const int r = i >> 9, c = i & 511;
    ushort4 o = make_ushort4(0, 0, 0, 0);
    if (r < 96) {
      const float4 v = ((const float4*)wx)[(size_t)r * 512 + c];
      o = make_ushort4(f2bf(v.x), f2bf(v.y), f2bf(v.z), f2bf(v.w));
    }
    ((ushort4*)wxb)[i] = o;
  } else {
    const int i = (bid - 8576) * 256 + threadIdx.x;   // 4194304 f4 (recon_w)
    const float4 v = ((const float4*)wr)[i];
    ((ushort4*)wrb)[i] = make_ushort4(f2bf(v.x), f2bf(v.y), f2bf(v.z), f2bf(v.w));
  }
}

// x_proj split-K reduce (8 slices) + dt slice -> bf16
__global__ __launch_bounds__(256) void reduce8_dt_kernel(
    const float* __restrict__ in, float* __restrict__ xdbl, uint16_t* __restrict__ dtb) {
  const int i = blockIdx.x * 256 + threadIdx.x;   // 262144 = 2048*128
  float s = 0.f;
#pragma unroll
  for (int z = 0; z < 8; ++z) s += in[i + (size_t)z * 262144];
  xdbl[i] = s;
  const int c = i & 127;
  if (c < 64) dtb[(i >> 7) * 64 + c] = f2bf(s);
}

// out_proj split-K reduce (2 slices) -> bf16 h2
__global__ __launch_bounds__(256) void reduce2_bf16_kernel(
    const float* __restrict__ in, uint16_t* __restrict__ outb, int n) {
  const int i = blockIdx.x * 256 + threadIdx.x;
  if (i >= n) return;
  outb[i] = f2bf(in[i] + in[i + (size_t)n]);
}

// causal conv (K=4) + bias + silu; bf16 in/out. 4 d per thread.
__global__ __launch_bounds__(256) void conv_silu_kernel(
    const uint16_t* __restrict__ xzb, const float* __restrict__ cw, const float* __restrict__ cb,
    uint16_t* __restrict__ xcb)
{
  const int idx = blockIdx.x * 256 + threadIdx.x;  // (m, d/4): 2048*512 total
  const int d4  = idx & 511;
  const int m   = idx >> 9;
  const int l   = m & (LSEQ - 1);
  const int d   = d4 << 2;
  const float4 cbv = *(const float4*)(cb + d);
  float a0 = cbv.x, a1 = cbv.y, a2 = cbv.z, a3 = cbv.w;
  const float4 w0 = *(const float4*)(cw + (d + 0) * 4);
  const float4 w1 = *(const float4*)(cw + (d + 1) * 4);
  const float4 w2 = *(const float4*)(cw + (d + 2) * 4);
  const float4 w3 = *(const float4*)(cw + (d + 3) * 4);
  const float wj0[4] = {w0.x, w0.y, w0.z, w0.w};
  const float wj1[4] = {w1.x, w1.y, w1.z, w1.w};
  const float wj2[4] = {w2.x, w2.y, w2.z, w2.w};
  const float wj3[4] = {w3.x, w3.y, w3.z, w3.w};
#pragma unroll
  for (int j = 0; j < 4; ++j) {
    const int lj = l - 3 + j;
    if (lj >= 0) {
      const ushort4 x = *(const ushort4*)(xzb + (size_t)(m - 3 + j) * 4096 + d);
      a0 += wj0[j] * bf2f(x.x);
      a1 += wj1[j] * bf2f(x.y);
      a2 += wj2[j] * bf2f(x.z);
      a3 += wj3[j] * bf2f(x.w);
    }
  }
  const float r0 = a0 / (1.f + __expf(-a0));
  const float r1 = a1 / (1.f + __expf(-a1));
  const float r2 = a2 / (1.f + __expf(-a2));
  const float r3 = a3 / (1.f + __expf(-a3));
  *(ushort4*)(xcb + (size_t)m * DIN + d) = make_ushort4(f2bf(r0), f2bf(r1), f2bf(r2), f2bf(r3));
}

// ---------------------------------------------------------------------------
// chunked scan, r8 q-split layout (measured best): thread per (d,q), 4 states.
// scan_final composes its own boundary state from P/Q (<=7 fused steps).
// ---------------------------------------------------------------------------
__global__ __launch_bounds__(256) void scan_partial_kernel(
    const uint16_t* __restrict__ delta_bf, const uint16_t* __restrict__ xcb,
    const float* __restrict__ xdbl, const float* __restrict__ A_log,
    float* __restrict__ Pb, float* __restrict__ Qb)
{
  const int q = threadIdx.x & 3;
  const int d_idx = threadIdx.x >> 2;
  const int c = blockIdx.x;
  const int d = blockIdx.y * 64 + d_idx;
  const int b = blockIdx.z;
  float Arow[4];
#pragma unroll
  for (int n = 0; n < 4; ++n)
    Arow[n] = -expf(A_log[d * 16 + q * 4 + n]);
  float P[4] = {1.f, 1.f, 1.f, 1.f};
  float Q[4] = {0.f, 0.f, 0.f, 0.f};
  const int l0 = c * CL;
#pragma unroll 4
  for (int li = 0; li < CL; ++li) {
    const int m = b * LSEQ + l0 + li;
    const float de = bf2f(delta_bf[(size_t)m * DIN + d]);
    const float xv = bf2f(xcb[(size_t)m * DIN + d]);
    const float dx = de * xv;
    const float4 Bv = *(const float4*)(xdbl + (size_t)m * 128 + 64 + q * 4);
    const float bv[4] = {Bv.x, Bv.y, Bv.z, Bv.w};
#pragma unroll
    for (int n = 0; n < 4; ++n) {
      const float a = __expf(de * Arow[n]);
      P[n] *= a;
      Q[n] = a * Q[n] + dx * bv[n];
    }
  }
  const size_t o = ((size_t)(b * NC + c) * DIN + d) * 16 + q * 4;
  *(float4*)(Pb + o) = make_float4(P[0], P[1], P[2], P[3]);
  *(float4*)(Qb + o) = make_float4(Q[0], Q[1], Q[2], Q[3]);
}

__global__ __launch_bounds__(256) void scan_final_kernel(
    const uint16_t* __restrict__ delta_bf, const uint16_t* __restrict__ xcb,
    const float* __restrict__ xdbl, const uint16_t* __restrict__ xzb,
    const float* __restrict__ A_log, const float* __restrict__ Dp,
    const float* __restrict__ Pb, const float* __restrict__ Qb,
    uint16_t* __restrict__ yb)
{
  const int q = threadIdx.x & 3;
  const int d_idx = threadIdx.x >> 2;
  const int c = blockIdx.x;
  const int d = blockIdx.y * 64 + d_idx;
  const int b = blockIdx.z;
  float Arow[4];
#pragma unroll
  for (int n = 0; n < 4; ++n)
    Arow[n] = -expf(A_log[d * 16 + q * 4 + n]);
  const float dpd = Dp[d];
  float h[4] = {0.f, 0.f, 0.f, 0.f};
  for (int cc = 0; cc < c; ++cc) {
    const size_t o = ((size_t)(b * NC + cc) * DIN + d) * 16 + q * 4;
    const float4 P4 = *(const float4*)(Pb + o);
    const float4 Q4 = *(const float4*)(Qb + o);
    h[0] = P4.x * h[0] + Q4.x;
    h[1] = P4.y * h[1] + Q4.y;
    h[2] = P4.z * h[2] + Q4.z;
    h[3] = P4.w * h[3] + Q4.w;
  }
  const int l0 = c * CL;
#pragma unroll 2
  for (int li = 0; li < CL; ++li) {
    const int m = b * LSEQ + l0 + li;
    const float de = bf2f(delta_bf[(size_t)m * DIN + d]);
    const float xv = bf2f(xcb[(size_t)m * DIN + d]);
    const float dx = de * xv;
    const float4 Bv = *(const float4*)(xdbl + (size_t)m * 128 + 64 + q * 4);
    const float4 Cv = *(const float4*)(xdbl + (size_t)m * 128 + 80 + q * 4);
    const float bv[4] = {Bv.x, Bv.y, Bv.z, Bv.w};
    const float cv[4] = {Cv.x, Cv.y, Cv.z, Cv.w};
    float yp = 0.f;
#pragma unroll
    for (int n = 0; n < 4; ++n) {
      const float a = __expf(de * Arow[n]);
      h[n] = a * h[n] + dx * bv[n];
      yp += h[n] * cv[n];
    }
    yp += __shfl_xor(yp, 1);
    yp += __shfl_xor(yp, 2);
    if (q == 0) {
      const float z = bf2f(xzb[(size_t)m * 4096 + 2048 + d]);
      const float sil = z / (1.f + __expf(-z));
      yb[(size_t)m * DIN + d] = f2bf((yp + xv * dpd) * sil);
    }
  }
}

// mean-pool partials: block (b,s) sums 32 L-rows of bf16 h2
__global__ __launch_bounds__(256) void pool1_kernel(
    const uint16_t* __restrict__ h2b, float* __restrict__ part) {
  const int b = blockIdx.x >> 4, s = blockIdx.x & 15;
  const int c = threadIdx.x * 4;
  const uint16_t* base = h2b + ((size_t)(b * LSEQ + s * 32)) * DMODEL + c;
  float a0 = 0, a1 = 0, a2 = 0, a3 = 0;
  for (int l = 0; l < 32; ++l) {
    const ushort4 v = *(const ushort4*)(base + (size_t)l * DMODEL);
    a0 += bf2f(v.x); a1 += bf2f(v.y); a2 += bf2f(v.z); a3 += bf2f(v.w);
  }
  *(float4*)(part + (size_t)blockIdx.x * DMODEL + c) = make_float4(a0, a1, a2, a3);
}

// final pool reduce + CLS head, one block per batch
__global__ __launch_bounds__(256) void pool2_cls_kernel(
    const float* __restrict__ part, const float* __restrict__ w, float* __restrict__ out) {
  __shared__ float pl[DMODEL];
  const int b = blockIdx.x, t = threadIdx.x;
  float4 s = make_float4(0, 0, 0, 0);
  for (int k = 0; k < 16; ++k) {
    const float4 v = *(const float4*)(part + ((size_t)(b * 16 + k)) * DMODEL + t * 4);
    s.x += v.x; s.y += v.y; s.z += v.z; s.w += v.w;
  }
  const float inv = 1.f / (float)LSEQ;
  pl[t * 4 + 0] = s.x * inv; pl[t * 4 + 1] = s.y * inv;
  pl[t * 4 + 2] = s.z * inv; pl[t * 4 + 3] = s.w * inv;
  __syncthreads();
  if (t < 128) {
    const float* wr = w + (size_t)t * DMODEL;
    float acc = 0.f;
    for (int k = 0; k < DMODEL; ++k) acc += pl[k] * wr[k];
    out[b * 128 + t] = acc;
  }
}

extern "C" void kernel_launch(void* const* d_in, const int* in_sizes, int n_in,
                              void* d_out, int out_size, void* d_ws, size_t ws_size,
                              hipStream_t stream) {
  const int*   tokens    = (const int*)d_in[0];
  const float* embedding = (const float*)d_in[1];
  const float* in_proj_w = (const float*)d_in[2];
  const float* conv_w    = (const float*)d_in[3];
  const float* conv_b    = (const float*)d_in[4];
  const float* x_proj_w  = (const float*)d_in[5];
  const float* dt_proj_w = (const float*)d_in[6];
  const float* dt_proj_b = (const float*)d_in[7];
  const float* A_log     = (const float*)d_in[8];
  const float* D_param   = (const float*)d_in[9];
  const float* out_prj_w = (const float*)d_in[10];
  const float* recon_w   = (const float*)d_in[11];
  const float* cls_w     = (const float*)d_in[12];

  char* ws = (char*)d_ws;
  const size_t MB = 1024 * 1024;
  uint16_t* h_bf   = (uint16_t*)(ws + 0);                 // 0-4   [dead after in_proj]
  uint16_t* w_in   = (uint16_t*)(ws + 4 * MB);            // 4-12  [dead after in_proj]
  uint16_t* xz_bf  = (uint16_t*)(ws + 12 * MB);           // 12-28 [dead after scan_final]
  uint16_t* xc_b   = (uint16_t*)(ws + 28 * MB);           // 28-36
  uint16_t* wx_bf  = (uint16_t*)(ws + 36 * MB);           // 36-36.5
  uint16_t* dt_bf  = (uint16_t*)(ws + 36 * MB + 512 * 1024);   // 36.5-36.75
  uint16_t* wdt_bf = (uint16_t*)(ws + 36 * MB + 768 * 1024);   // 36.75-37
  float*    xdbl   = (float*)(ws + 37 * MB);              // 37-38
  uint16_t* delt_b = (uint16_t*)(ws + 38 * MB);           // 38-46 (bf16 delta)
  float*    kscr   = (float*)(ws + 46 * MB);              // 46-54 (x_proj splitK x8; dead after reduce8)
  uint16_t* y_bf   = (uint16_t*)(ws + 54 * MB);           // 54-62
  uint16_t* h2_bf  = (uint16_t*)(ws + 62 * MB);           // 62-66
  uint16_t* wout_bf= (uint16_t*)(ws + 66 * MB);           // 66-70
  float*    part   = (float*)(ws + 70 * MB);              // 70-70.25
  uint16_t* wrec_bf= (uint16_t*)(ws + 71 * MB);           // 71-103 (written step 1, read by recon)
  // aliases (lifetime-disjoint)
  float*    Pbuf   = (float*)(ws + 46 * MB);              // 46-50 (kscr dead)
  float*    Qbuf   = (float*)(ws + 50 * MB);              // 50-54
  float*    kscr2  = (float*)(ws + 4 * MB);               // 4-20 (w_in + xz_bf dead by out_proj)

  const int RECON = MROWS * NV;

  // 1. ALL conversions (incl. recon_w) + embedding gather, one launch
  mega_cvt_kernel<<<dim3(24960), dim3(256), 0, stream>>>(
      tokens, embedding, in_proj_w, out_prj_w, dt_proj_w, x_proj_w, recon_w,
      h_bf, w_in, wout_bf, wdt_bf, wx_bf, wrec_bf);
  // 2. in_proj: 2048 x 4096, K=1024 -> bf16 xz directly
  gemm_bf16_kernel<<<dim3(32, 16, 1), dim3(256), 0, stream>>>(h_bf, w_in, nullptr, xz_bf, MROWS, 4096, 1024, 1024, nullptr);
  // 3. causal conv + silu (bf16 in/out)
  conv_silu_kernel<<<dim3(4096), dim3(256), 0, stream>>>(xz_bf, conv_w, conv_b, xc_b);
  // 4. x_dbl = x @ x_proj_w^T (split-K x8 -> 128 blocks)
  gemm_bf16_kernel<<<dim3(1, 16, 8), dim3(256), 0, stream>>>(xc_b, wx_bf, kscr, nullptr, MROWS, 128, 2048, 256, nullptr);
  reduce8_dt_kernel<<<dim3(1024), dim3(256), 0, stream>>>(kscr, xdbl, dt_bf);
  // 5. delta = softplus(dt @ dt_proj_w^T + b) -> bf16
  gemm_bf16_kernel<<<dim3(16, 16, 1), dim3(256), 0, stream>>>(dt_bf, wdt_bf, nullptr, delt_b, MROWS, DIN, 64, 64, dt_proj_b);
  // 6. chunked selective scan (bounds folded into scan_final prologue)
  scan_partial_kernel<<<dim3(NC, 32, 4), dim3(256), 0, stream>>>(delt_b, xc_b, xdbl, A_log, Pbuf, Qbuf);
  scan_final_kernel<<<dim3(NC, 32, 4), dim3(256), 0, stream>>>(delt_b, xc_b, xdbl, xz_bf, A_log, D_param, Pbuf, Qbuf, y_bf);
  // 7. out_proj: split-K x2 (256 blocks) + bf16 reduce
  gemm_bf16_kernel<<<dim3(8, 16, 2), dim3(256), 0, stream>>>(y_bf, wout_bf, kscr2, nullptr, MROWS, 1024, 2048, 1024, nullptr);
  reduce2_bf16_kernel<<<dim3(8192), dim3(256), 0, stream>>>(kscr2, h2_bf, MROWS * 1024);
  // 8. recon: 2048 x 16384, K=1024 (r3 4-slot ring, 16x16x32 — measured best)
  gemm256_bf16_kernel<<<dim3(512), dim3(512), 0, stream>>>(h2_bf, wrec_bf, (float*)d_out, MROWS, NV, 1024);
  // 9. CLS head
  pool1_kernel<<<dim3(64), dim3(256), 0, stream>>>(h2_bf, part);
  pool2_cls_kernel<<<dim3(4), dim3(256), 0, stream>>>(part, cls_w, (float*)d_out + RECON);
}